// Round 2
// baseline (499.475 us; speedup 1.0000x reference)
//
#include <hip/hip_runtime.h>
#include <hip/hip_bf16.h>
#include <stdint.h>

#define NTOK 49
#define DIMC 128
#define NHEAD 4
#define SCALE 0.17677669529663687f

typedef __bf16 bf16;
typedef __bf16 bf16x8 __attribute__((ext_vector_type(8)));
typedef __bf16 bf16x4 __attribute__((ext_vector_type(4)));
typedef float  f32x4  __attribute__((ext_vector_type(4)));
typedef short  s16x4  __attribute__((ext_vector_type(4)));

// ---- LDS layout (bf16 elems), total 17920 elems = 35840 B -> 4 blocks/CU ----
// K  @0   : rows [h*64+tok] stride 36 (K[tok][d], transpose-stored)
// VT @9216: rows [h*32+d]  stride 68 (V^T[d][tok], transpose-stored)
// Q, P, O^T never touch LDS: the 16x16x16 MFMA B-fragment layout
// (k=quad*4+i, col=ln15) equals the C layout (row=quad*4+r, col=ln15),
// so each stage's C packs directly into the next stage's B operand.
#define QK_S 36
#define VT_S 68
#define VT_OFF 9216
#define SM_ELEMS 17920

// d_ws layout (bytes): comb bf16 [64][64][4][64] @0 (2 MB);
// qkvw bf16 @2097152 (98304 B); projw bf16 @2195456 (32768 B)
#define WS_QKVW_OFF 2097152
#define WS_PROJW_OFF 2195456

__device__ __forceinline__ f32x4 mfmaK32(bf16x8 a, bf16x8 b, f32x4 c) {
  return __builtin_amdgcn_mfma_f32_16x16x32_bf16(a, b, c, 0, 0, 0);
}
__device__ __forceinline__ f32x4 mfmaK16(bf16x4 a, bf16x4 b, f32x4 c) {
#if __has_builtin(__builtin_amdgcn_mfma_f32_16x16x16bf16_1k)
  return __builtin_amdgcn_mfma_f32_16x16x16bf16_1k(*(s16x4*)&a, *(s16x4*)&b, c,
                                                   0, 0, 0);
#else
  f32x4 d;
  asm("v_mfma_f32_16x16x16_bf16 %0, %1, %2, %3"
      : "=v"(d) : "v"(a), "v"(b), "v"(c));
  return d;
#endif
}
__device__ __forceinline__ bf16x8 cvt8(const float* __restrict__ p) {
  f32x4 a = *(const f32x4*)p;
  f32x4 c = *(const f32x4*)(p + 4);
  bf16x8 r;
#pragma unroll
  for (int j = 0; j < 4; ++j) { r[j] = (bf16)a[j]; r[4 + j] = (bf16)c[j]; }
  return r;
}

// ---------------- prologue: build comb table + bf16 weights in d_ws ----------
__global__ __launch_bounds__(256)
void prep(const float* __restrict__ maskg, const float* __restrict__ rpb,
          const int* __restrict__ rel, const float* __restrict__ qkvw,
          const float* __restrict__ projw, bf16* __restrict__ comb,
          bf16* __restrict__ qkvw_b, bf16* __restrict__ projw_b) {
  int id = blockIdx.x * 256 + threadIdx.x;
  if (id < 64 * 64 * 4 * 64) {
    // comb[win][n][h][m] = mask[win][n][m] + rpb[rel[n][m]][h], -30000 at pads
    int m = id & 63, h = (id >> 6) & 3, n = (id >> 8) & 63, win = id >> 14;
    float v = -30000.0f;
    if (n < NTOK && m < NTOK)
      v = maskg[((size_t)win * NTOK + n) * NTOK + m] + rpb[rel[n * NTOK + m] * 4 + h];
    comb[id] = (bf16)v;
  } else {
    int t = id - 64 * 64 * 4 * 64;          // 0..65535
    if (t < 384 * 128) qkvw_b[t] = (bf16)qkvw[t];
    else               projw_b[t - 384 * 128] = (bf16)projw[t - 384 * 128];
  }
}

// ---------------- main kernel: one window per block, 4 waves ----------------
// Wave w owns tokens [w*16, w*16+16) for EVERYTHING: loads only those 16 x
// rows (16 VGPRs), computes q/K/V across all 128 dims (8 j-tiles each).
// x is read exactly once -> minimal HBM traffic at 4 blocks/CU.
__global__ __launch_bounds__(256, 4)
void winattn(const float* __restrict__ xg, const float* __restrict__ qkvb,
             const float* __restrict__ projb, const bf16* __restrict__ comb,
             const bf16* __restrict__ qkvw_b, const bf16* __restrict__ projw_b,
             float* __restrict__ out) {
  __shared__ bf16 sm[SM_ELEMS];

  const int b    = blockIdx.x;
  const int tid  = threadIdx.x;
  const int w    = tid >> 6;        // wave id == token group (both phases)
  const int lane = tid & 63;
  const int ln15 = lane & 15;
  const int quad = lane >> 4;
  const int nq   = w * 16 + ln15;   // this lane's token column

  // ---- x rows for this wave's 16 tokens only (rows>=49 clamped; pad rows
  // are neutralized downstream by comb=-30000 and the output guard) ----
  const float* xb = xg + (size_t)b * (NTOK * DIMC);
  const float* xqr = xb + (nq < NTOK ? nq : (NTOK - 1)) * DIMC;
  bf16x8 xq[4];
#pragma unroll
  for (int ks = 0; ks < 4; ++ks) xq[ks] = cvt8(&xqr[ks * 32 + quad * 8]);

  // ---- K for tokens [w*16,+16), all 128 k-dims: C[j][tok] -> K[tok][d] ----
#pragma unroll
  for (int tq = 0; tq < 8; ++tq) {
    const int j0 = DIMC + tq * 16;
    f32x4 acc = (f32x4)(0.0f);
#pragma unroll
    for (int ks = 0; ks < 4; ++ks) {
      bf16x8 wf = *(const bf16x8*)&qkvw_b[(size_t)(j0 + ln15) * DIMC + ks * 32 + quad * 8];
      acc = mfmaK32(wf, xq[ks], acc);
    }
    f32x4 b4 = *(const f32x4*)&qkvb[j0 + quad * 4];
    bf16x4 pk;
#pragma unroll
    for (int r = 0; r < 4; ++r) pk[r] = (bf16)(acc[r] + b4[r]);
    // j = tq*16+quad*4+r -> head h=tq>>1, d=(tq&1)*16+quad*4+r; tok=w*16+ln15
    *(bf16x4*)&sm[((tq >> 1) * 64 + w * 16 + ln15) * QK_S + (tq & 1) * 16 + quad * 4] = pk;
  }

  // ---- V for tokens [w*16,+16): C[tok][j] -> VT[d][tok] ----
#pragma unroll
  for (int tq = 0; tq < 8; ++tq) {
    const int j0 = 2 * DIMC + tq * 16;
    f32x4 acc = (f32x4)(0.0f);
#pragma unroll
    for (int ks = 0; ks < 4; ++ks) {
      bf16x8 wf = *(const bf16x8*)&qkvw_b[(size_t)(j0 + ln15) * DIMC + ks * 32 + quad * 8];
      acc = mfmaK32(xq[ks], wf, acc);
    }
    float bv = qkvb[j0 + ln15];
    bf16x4 pk;
#pragma unroll
    for (int r = 0; r < 4; ++r) pk[r] = (bf16)(acc[r] + bv);
    // tok = w*16+quad*4+r; j = tq*16+ln15 -> h=tq>>1, d=(tq&1)*16+ln15
    *(bf16x4*)&sm[VT_OFF + ((tq >> 1) * 32 + (tq & 1) * 16 + ln15) * VT_S + w * 16 + quad * 4] = pk;
  }

  // ---- q: all 128 rows for own tokens; stays in registers as B-frags.
  // C[j=quad*4+r][tok=ln15] is directly the 16x16x16 B-frag for k-tile tq. ----
  bf16x4 qw[8];
#pragma unroll
  for (int tq = 0; tq < 8; ++tq) {
    const int j0 = tq * 16;
    f32x4 acc = (f32x4)(0.0f);
#pragma unroll
    for (int ks = 0; ks < 4; ++ks) {
      bf16x8 wf = *(const bf16x8*)&qkvw_b[(size_t)(j0 + ln15) * DIMC + ks * 32 + quad * 8];
      acc = mfmaK32(wf, xq[ks], acc);
    }
    f32x4 b4 = *(const f32x4*)&qkvb[j0 + quad * 4];
#pragma unroll
    for (int r = 0; r < 4; ++r) qw[tq][r] = (bf16)((acc[r] + b4[r]) * SCALE);
  }

  // ---- combined bias (mask+rpb): L2 loads, issued BEFORE the barrier so
  // their latency hides under the barrier wait (compiler can't hoist them) ----
  const bf16* cbase = comb + ((size_t)(b & 63) * 64 + nq) * (4 * 64);
  bf16x4 combv[NHEAD][4];
#pragma unroll
  for (int h = 0; h < NHEAD; ++h)
#pragma unroll
    for (int mt = 0; mt < 4; ++mt)
      combv[h][mt] = *(const bf16x4*)&cbase[h * 64 + mt * 16 + quad * 4];

  __syncthreads();   // K, VT visible to all waves — the ONLY barrier

  // ---- phase 2: per-head attention, fully in registers except K/VT reads ----
  bf16x4 ow[8];      // O^T bf16, B-frags for proj (k-tile = 2h+dt)
#pragma unroll
  for (int h = 0; h < NHEAD; ++h) {
    // S^T tile: A = K[m][d] (b64 LDS reads), B = qw -> C[m%16][nq]
    f32x4 st[4];
#pragma unroll
    for (int mt = 0; mt < 4; ++mt) {
      const bf16* kr = &sm[(h * 64 + mt * 16 + ln15) * QK_S + quad * 4];
      bf16x4 k0 = *(const bf16x4*)kr;          // d = quad*4+i
      bf16x4 k1 = *(const bf16x4*)(kr + 16);   // d = 16+quad*4+i
      st[mt] = mfmaK16(k1, qw[2 * h + 1], mfmaK16(k0, qw[2 * h], (f32x4)(0.0f)));
    }
    // exp(logit+bias) without max-sub (bounded; clamp 60; -30000 underflows->0)
    float ssum = 0.0f;
#pragma unroll
    for (int mt = 0; mt < 4; ++mt)
#pragma unroll
      for (int r = 0; r < 4; ++r) {
        float v = fminf(st[mt][r] + (float)combv[h][mt][r], 60.0f);
        float p = __expf(v);
        st[mt][r] = p;
        ssum += p;
      }
    // P^T C-layout == PV B-frag layout: pack in-register, no LDS round trip
    bf16x4 pw[4];
#pragma unroll
    for (int mt = 0; mt < 4; ++mt)
#pragma unroll
      for (int r = 0; r < 4; ++r) pw[mt][r] = (bf16)st[mt][r];
    ssum += __shfl_xor(ssum, 16);
    ssum += __shfl_xor(ssum, 32);
    // O^T = V^T·P^T : A = VT rows (b64 LDS reads), B = pw
    f32x4 oa[2];
#pragma unroll
    for (int dt = 0; dt < 2; ++dt) {
      const bf16* vr = &sm[VT_OFF + (h * 32 + dt * 16 + ln15) * VT_S + quad * 4];
      f32x4 a = (f32x4)(0.0f);
#pragma unroll
      for (int mt = 0; mt < 4; ++mt)
        a = mfmaK16(*(const bf16x4*)(vr + mt * 16), pw[mt], a);
      oa[dt] = a;
    }
    const float inv = 1.0f / ssum;
#pragma unroll
    for (int dt = 0; dt < 2; ++dt)
#pragma unroll
      for (int r = 0; r < 4; ++r) ow[2 * h + dt][r] = (bf16)(oa[dt][r] * inv);
  }

  // ---- proj GEMM: Y^T = projW·O^T, K=128 as 8 k-tiles of 16; O^T already in
  // B-frag form (ow). Weights: 8B loads, L2-resident, freely hoistable. ----
  f32x4 yacc[8];
#pragma unroll
  for (int jt = 0; jt < 8; ++jt) {
    f32x4 a = (f32x4)(0.0f);
#pragma unroll
    for (int kt = 0; kt < 8; ++kt) {
      bf16x4 aw = *(const bf16x4*)&projw_b[(size_t)(jt * 16 + ln15) * DIMC + kt * 16 + quad * 4];
      a = mfmaK16(aw, ow[kt], a);
    }
    yacc[jt] = a;
  }

  // ---- epilogue: + projb, fp32 16B stores; lane column = token nq ----
  if (nq < NTOK) {
    float* ob = out + (size_t)b * (NTOK * DIMC) + nq * DIMC;
#pragma unroll
    for (int jt = 0; jt < 8; ++jt) {
      f32x4 pbv = *(const f32x4*)&projb[jt * 16 + quad * 4];
      f32x4 y;
#pragma unroll
      for (int r = 0; r < 4; ++r) y[r] = yacc[jt][r] + pbv[r];
      *(f32x4*)&ob[jt * 16 + quad * 4] = y;
    }
  }
}

extern "C" void kernel_launch(void* const* d_in, const int* in_sizes, int n_in,
                              void* d_out, int out_size, void* d_ws, size_t ws_size,
                              hipStream_t stream) {
  const float* x     = (const float*)d_in[0];
  const float* mask  = (const float*)d_in[1];
  const float* qkv_w = (const float*)d_in[2];
  const float* qkv_b = (const float*)d_in[3];
  const float* rpb   = (const float*)d_in[4];
  const float* prj_w = (const float*)d_in[5];
  const float* prj_b = (const float*)d_in[6];
  const int*   rel   = (const int*)d_in[7];
  float* out = (float*)d_out;

  bf16* ws_comb  = (bf16*)d_ws;
  bf16* ws_qkvw  = (bf16*)((char*)d_ws + WS_QKVW_OFF);
  bf16* ws_projw = (bf16*)((char*)d_ws + WS_PROJW_OFF);

  const int B = in_sizes[0] / (NTOK * DIMC);   // 4096
  prep<<<4352, 256, 0, stream>>>(mask, rpb, rel, qkv_w, prj_w,
                                 ws_comb, ws_qkvw, ws_projw);
  winattn<<<B, 256, 0, stream>>>(x, qkv_b, prj_b, ws_comb, ws_qkvw, ws_projw, out);
}

// Round 3
// 291.661 us; speedup vs baseline: 1.7125x; 1.7125x over previous
//
#include <hip/hip_runtime.h>
#include <hip/hip_bf16.h>
#include <stdint.h>

#define NTOK 49
#define DIMC 128
#define NHEAD 4
#define SCALE 0.17677669529663687f

typedef __bf16 bf16;
typedef __bf16 bf16x8 __attribute__((ext_vector_type(8)));
typedef __bf16 bf16x4 __attribute__((ext_vector_type(4)));
typedef float  f32x4  __attribute__((ext_vector_type(4)));
typedef short  s16x4  __attribute__((ext_vector_type(4)));

// ---- dynamic LDS layout (bf16 elems), total 69632 elems = 139264 B ----
// qw_lds @0     : q-weight rows j in [0,128), stride 132  (16896 elems)
// pw_lds @16896 : proj-weight rows, stride 132            (16896 elems)
// per-half window region @33792 + half*17920:
//   K  @+0    rows [h*64+tok] stride 36  (K[tok][d], transpose-stored)
//   VT @+9216 rows [h*32+d ] stride 68   (V^T[d][tok])
#define QW_LDS 0
#define PW_LDS 16896
#define WIN_LDS 33792
#define HALF_ELEMS 17920
#define K_OFF 0
#define VT_OFF 9216
#define QK_S 36
#define VT_S 68
#define W_S 132
#define SM_BYTES ((33792 + 2 * 17920) * 2)   // 139264

// d_ws layout (bytes): comb bf16 [64][64][4][quad][mt][r] @0 (2 MB);
// qkvw bf16 @2097152 (98304 B); projw bf16 @2195456 (32768 B)
#define WS_QKVW_OFF 2097152
#define WS_PROJW_OFF 2195456

__device__ __forceinline__ f32x4 mfmaK32(bf16x8 a, bf16x8 b, f32x4 c) {
  return __builtin_amdgcn_mfma_f32_16x16x32_bf16(a, b, c, 0, 0, 0);
}
__device__ __forceinline__ f32x4 mfmaK16(bf16x4 a, bf16x4 b, f32x4 c) {
#if __has_builtin(__builtin_amdgcn_mfma_f32_16x16x16bf16_1k)
  return __builtin_amdgcn_mfma_f32_16x16x16bf16_1k(*(s16x4*)&a, *(s16x4*)&b, c,
                                                   0, 0, 0);
#else
  f32x4 d;
  asm("v_mfma_f32_16x16x16_bf16 %0, %1, %2, %3"
      : "=v"(d) : "v"(a), "v"(b), "v"(c));
  return d;
#endif
}
__device__ __forceinline__ bf16x8 ld8(const bf16* p) {
  bf16x4 lo = *(const bf16x4*)p, hi = *(const bf16x4*)(p + 4);
  bf16x8 r;
#pragma unroll
  for (int j = 0; j < 4; ++j) { r[j] = lo[j]; r[4 + j] = hi[j]; }
  return r;
}
__device__ __forceinline__ bf16x8 cvt8(const float* __restrict__ p) {
  f32x4 a = *(const f32x4*)p;
  f32x4 c = *(const f32x4*)(p + 4);
  bf16x8 r;
#pragma unroll
  for (int j = 0; j < 4; ++j) { r[j] = (bf16)a[j]; r[4 + j] = (bf16)c[j]; }
  return r;
}
// 16B global read -> two 8B LDS writes (W_S=132 rows are only 8B-aligned)
__device__ __forceinline__ void stage8(bf16* dst, const bf16* src) {
  bf16x8 v = *(const bf16x8*)src;
  bf16x4 lo, hi;
#pragma unroll
  for (int j = 0; j < 4; ++j) { lo[j] = v[j]; hi[j] = v[4 + j]; }
  *(bf16x4*)dst = lo;
  *(bf16x4*)(dst + 4) = hi;
}

// ---------------- prologue: build comb table + bf16 weights in d_ws ----------
__global__ __launch_bounds__(256)
void prep(const float* __restrict__ maskg, const float* __restrict__ rpb,
          const int* __restrict__ rel, const float* __restrict__ qkvw,
          const float* __restrict__ projw, bf16* __restrict__ comb,
          bf16* __restrict__ qkvw_b, bf16* __restrict__ projw_b) {
  int id = blockIdx.x * 256 + threadIdx.x;
  if (id < 64 * 64 * 4 * 64) {
    // comb[win][n][h][quad][mt][r] = mask[win][n][m] + rpb[rel[n][m]][h],
    // m = mt*16 + quad*4 + r; -30000 at pads. Lane-sliced for 16B loads.
    int c = id & 63, h = (id >> 6) & 3, n = (id >> 8) & 63, win = id >> 14;
    int qd = (c >> 4) & 3, mt = (c >> 2) & 3, r = c & 3;
    int m = mt * 16 + qd * 4 + r;
    float v = -30000.0f;
    if (n < NTOK && m < NTOK)
      v = maskg[((size_t)win * NTOK + n) * NTOK + m] + rpb[rel[n * NTOK + m] * 4 + h];
    comb[id] = (bf16)v;
  } else {
    int t = id - 64 * 64 * 4 * 64;          // 0..65535
    if (t < 384 * 128) qkvw_b[t] = (bf16)qkvw[t];
    else               projw_b[t - 384 * 128] = (bf16)projw[t - 384 * 128];
  }
}

// ---------------- main kernel: persistent, 2 windows per iteration ----------
// grid = 256 blocks x 512 threads (8 waves): waves 0-3 handle window slot 0,
// waves 4-7 slot 1; each block loops over 16 windows (8 iterations x 2).
// k/v weight fragments live in VGPRs (loaded once); q-weights + proj-weights
// staged once into LDS -> per-window global traffic is only x + comb + out.
__global__ __launch_bounds__(512, 2)
void winattn(const float* __restrict__ xg, const float* __restrict__ qkvb,
             const float* __restrict__ projb, const bf16* __restrict__ comb,
             const bf16* __restrict__ qkvw_b, const bf16* __restrict__ projw_b,
             float* __restrict__ out) {
  extern __shared__ bf16 smd[];

  const int tid  = threadIdx.x;
  const int w8   = tid >> 6;        // 0..7
  const int half = w8 >> 2;         // window slot
  const int hw   = w8 & 3;          // head id (k/v) == token group (x/q/phase2)
  const int lane = tid & 63;
  const int ln15 = lane & 15;
  const int quad = lane >> 4;
  const int nq   = hw * 16 + ln15;  // this lane's token column

  bf16* __restrict__ qwl = smd + QW_LDS;
  bf16* __restrict__ pwl = smd + PW_LDS;
  bf16* __restrict__ smw = smd + WIN_LDS + half * HALF_ELEMS;

  // ---- one-time: stage q-weights + proj-weights into LDS (all 512 thr) ----
#pragma unroll
  for (int i = 0; i < 4; ++i) {
    int c = i * 512 + tid;                  // chunk 0..2047
    int j = c >> 4, kc = (c & 15) * 8;
    stage8(&qwl[j * W_S + kc], &qkvw_b[j * DIMC + kc]);
    stage8(&pwl[j * W_S + kc], &projw_b[(size_t)j * DIMC + kc]);
  }

  // ---- one-time: k/v weight fragments + k/v biases into registers ----
  bf16x8 wk[2][4], wv[2][4];
  f32x4 kb[2]; float vb[2];
#pragma unroll
  for (int t = 0; t < 2; ++t) {
    const int jk = DIMC + hw * 32 + t * 16;
    const int jv = 2 * DIMC + hw * 32 + t * 16;
#pragma unroll
    for (int ks = 0; ks < 4; ++ks) {
      wk[t][ks] = *(const bf16x8*)&qkvw_b[(size_t)(jk + ln15) * DIMC + ks * 32 + quad * 8];
      wv[t][ks] = *(const bf16x8*)&qkvw_b[(size_t)(jv + ln15) * DIMC + ks * 32 + quad * 8];
    }
    kb[t] = *(const f32x4*)&qkvb[jk + quad * 4];
    vb[t] = qkvb[jv + ln15];
  }
  __syncthreads();   // staged weight tables visible

  for (int it = 0; it < 8; ++it) {
    const int b = (blockIdx.x << 4) + (it << 1) + half;

    // ---- x frags, rotated token groups: g=(hw+i)&3 -> xf[0] is OWN group,
    // K/V keep 4-way ILP, x read exactly once, no runtime reg indexing ----
    const float* xb = xg + (size_t)b * (NTOK * DIMC);
    bf16x8 xf[4][4];
#pragma unroll
    for (int i = 0; i < 4; ++i) {
      int tok = ((hw + i) & 3) * 16 + ln15;
      const float* xr = xb + (tok < NTOK ? tok : (NTOK - 1)) * DIMC;
#pragma unroll
      for (int ks = 0; ks < 4; ++ks) xf[i][ks] = cvt8(&xr[ks * 32 + quad * 8]);
    }

    // ---- K (head hw, weights from regs): C[j][tok] -> K[tok][d] ----
#pragma unroll
    for (int t = 0; t < 2; ++t)
#pragma unroll
      for (int i = 0; i < 4; ++i) {
        int g = (hw + i) & 3;
        f32x4 acc = (f32x4)(0.0f);
#pragma unroll
        for (int ks = 0; ks < 4; ++ks) acc = mfmaK32(wk[t][ks], xf[i][ks], acc);
        bf16x4 pk;
#pragma unroll
        for (int r = 0; r < 4; ++r) pk[r] = (bf16)(acc[r] + kb[t][r]);
        *(bf16x4*)&smw[K_OFF + (hw * 64 + g * 16 + ln15) * QK_S + t * 16 + quad * 4] = pk;
      }

    // ---- V (head hw): C[tok][j] -> VT[d][tok] ----
#pragma unroll
    for (int t = 0; t < 2; ++t)
#pragma unroll
      for (int i = 0; i < 4; ++i) {
        int g = (hw + i) & 3;
        f32x4 acc = (f32x4)(0.0f);
#pragma unroll
        for (int ks = 0; ks < 4; ++ks) acc = mfmaK32(xf[i][ks], wv[t][ks], acc);
        bf16x4 pk;
#pragma unroll
        for (int r = 0; r < 4; ++r) pk[r] = (bf16)(acc[r] + vb[t]);
        *(bf16x4*)&smw[VT_OFF + (hw * 32 + t * 16 + ln15) * VT_S + g * 16 + quad * 4] = pk;
      }

    // ---- comb prefetch: 8x16B, latency hides under q-phase + barrier ----
    const bf16* cb = comb + ((size_t)(b & 63) * 64 + nq) * 256;
    bf16x8 cv[NHEAD][2];
#pragma unroll
    for (int h = 0; h < NHEAD; ++h) {
      cv[h][0] = *(const bf16x8*)&cb[h * 64 + quad * 16];
      cv[h][1] = *(const bf16x8*)&cb[h * 64 + quad * 16 + 8];
    }

    // ---- q (own tokens, all 128 rows): A from LDS, B = xf[0]; result stays
    // in registers as K16 B-frags (C layout == K16 B-frag layout) ----
    bf16x4 qw[8];
#pragma unroll
    for (int tq = 0; tq < 8; ++tq) {
      f32x4 acc = (f32x4)(0.0f);
#pragma unroll
      for (int ks = 0; ks < 4; ++ks) {
        bf16x8 aw = ld8(&qwl[(tq * 16 + ln15) * W_S + ks * 32 + quad * 8]);
        acc = mfmaK32(aw, xf[0][ks], acc);
      }
      f32x4 qb4 = *(const f32x4*)&qkvb[tq * 16 + quad * 4];   // L1-hot
#pragma unroll
      for (int r = 0; r < 4; ++r) qw[tq][r] = (bf16)((acc[r] + qb4[r]) * SCALE);
    }

    __syncthreads();   // K, VT of both halves ready

    // ---- phase 2: per-head attention, fully in registers except K/VT ----
    bf16x4 ow[8];      // O^T as K16 B-frags for proj (k-tile = 2h+dt)
#pragma unroll
    for (int h = 0; h < NHEAD; ++h) {
      f32x4 st[4];
#pragma unroll
      for (int mt = 0; mt < 4; ++mt) {
        const bf16* kr = &smw[K_OFF + (h * 64 + mt * 16 + ln15) * QK_S + quad * 4];
        bf16x4 k0 = *(const bf16x4*)kr;
        bf16x4 k1 = *(const bf16x4*)(kr + 16);
        st[mt] = mfmaK16(k1, qw[2 * h + 1], mfmaK16(k0, qw[2 * h], (f32x4)(0.0f)));
      }
      float ssum = 0.0f;
#pragma unroll
      for (int mt = 0; mt < 4; ++mt)
#pragma unroll
        for (int r = 0; r < 4; ++r) {
          float v = fminf(st[mt][r] + (float)cv[h][mt >> 1][(mt & 1) * 4 + r], 60.0f);
          float p = __expf(v);
          st[mt][r] = p;
          ssum += p;
        }
      bf16x4 pw[4];
#pragma unroll
      for (int mt = 0; mt < 4; ++mt)
#pragma unroll
        for (int r = 0; r < 4; ++r) pw[mt][r] = (bf16)st[mt][r];
      ssum += __shfl_xor(ssum, 16);
      ssum += __shfl_xor(ssum, 32);
      f32x4 oa[2];
#pragma unroll
      for (int dt = 0; dt < 2; ++dt) {
        const bf16* vr = &smw[VT_OFF + (h * 32 + dt * 16 + ln15) * VT_S + quad * 4];
        f32x4 a = (f32x4)(0.0f);
#pragma unroll
        for (int mt = 0; mt < 4; ++mt)
          a = mfmaK16(*(const bf16x4*)(vr + mt * 16), pw[mt], a);
        oa[dt] = a;
      }
      const float inv = 1.0f / ssum;
#pragma unroll
      for (int dt = 0; dt < 2; ++dt)
#pragma unroll
        for (int r = 0; r < 4; ++r) ow[2 * h + dt][r] = (bf16)(oa[dt][r] * inv);
    }

    // ---- proj: A from LDS-staged projw, B = ow (in regs) ----
    f32x4 yacc[8];
#pragma unroll
    for (int jt = 0; jt < 8; ++jt) {
      f32x4 a = (f32x4)(0.0f);
#pragma unroll
      for (int kt = 0; kt < 8; ++kt) {
        bf16x4 aw = *(const bf16x4*)&pwl[(jt * 16 + ln15) * W_S + kt * 16 + quad * 4];
        a = mfmaK16(aw, ow[kt], a);
      }
      yacc[jt] = a;
    }

    // ---- epilogue: + projb (L1-hot), fp32 16B stores ----
    if (nq < NTOK) {
      float* ob = out + (size_t)b * (NTOK * DIMC) + nq * DIMC;
#pragma unroll
      for (int jt = 0; jt < 8; ++jt) {
        f32x4 pbv = *(const f32x4*)&projb[jt * 16 + quad * 4];
        f32x4 y;
#pragma unroll
        for (int r = 0; r < 4; ++r) y[r] = yacc[jt][r] + pbv[r];
        *(f32x4*)&ob[jt * 16 + quad * 4] = y;
      }
    }

    __syncthreads();   // all K/VT reads done before next iteration overwrites
  }
}

extern "C" void kernel_launch(void* const* d_in, const int* in_sizes, int n_in,
                              void* d_out, int out_size, void* d_ws, size_t ws_size,
                              hipStream_t stream) {
  const float* x     = (const float*)d_in[0];
  const float* mask  = (const float*)d_in[1];
  const float* qkv_w = (const float*)d_in[2];
  const float* qkv_b = (const float*)d_in[3];
  const float* rpb   = (const float*)d_in[4];
  const float* prj_w = (const float*)d_in[5];
  const float* prj_b = (const float*)d_in[6];
  const int*   rel   = (const int*)d_in[7];
  float* out = (float*)d_out;

  bf16* ws_comb  = (bf16*)d_ws;
  bf16* ws_qkvw  = (bf16*)((char*)d_ws + WS_QKVW_OFF);
  bf16* ws_projw = (bf16*)((char*)d_ws + WS_PROJW_OFF);

  static int once = []() {
    hipFuncSetAttribute(reinterpret_cast<const void*>(winattn),
                        hipFuncAttributeMaxDynamicSharedMemorySize, SM_BYTES);
    return 0;
  }();
  (void)once;

  prep<<<4352, 256, 0, stream>>>(mask, rpb, rel, qkv_w, prj_w,
                                 ws_comb, ws_qkvw, ws_projw);
  winattn<<<256, 512, SM_BYTES, stream>>>(x, qkv_b, prj_b, ws_comb,
                                          ws_qkvw, ws_projw, out);
}

// Round 4
// 243.641 us; speedup vs baseline: 2.0500x; 1.1971x over previous
//
#include <hip/hip_runtime.h>
#include <hip/hip_bf16.h>
#include <stdint.h>

#define NTOK 49
#define DIMC 128
#define NHEAD 4
#define SCALE 0.17677669529663687f

typedef __bf16 bf16;
typedef __bf16 bf16x8 __attribute__((ext_vector_type(8)));
typedef __bf16 bf16x4 __attribute__((ext_vector_type(4)));
typedef float  f32x4  __attribute__((ext_vector_type(4)));
typedef short  s16x4  __attribute__((ext_vector_type(4)));

// ---- LDS layout (bf16 elems), total 61440 elems = 122880 B, 1 block/CU ----
// pw @0     : proj-weight rows stride 132                 (16896)
// K  @16896 : rows [h*64+tok] stride 36 (K[tok][d])       ( 9216)
// Q  @26112 : rows [h*64+tok] stride 36 (Q[tok][d])       ( 9216)
// VT @35328 : rows [h*32+d ] stride 68 (V^T[d][tok])      ( 8704)
// x0 @44032 : x rows [tok][d] stride 136, bf16            ( 8704)  (+O overlay)
// x1 @52736 : double buffer                               ( 8704)
// All read/write patterns bank-verified uniform (0 conflict); x stride 136
// keeps rows 16B-aligned for ds_*_b128.
#define PW_OFF 0
#define K_OFF  16896
#define Q_OFF  26112
#define VT_OFF 35328
#define X0_OFF 44032
#define X1_OFF 52736
#define QK_S 36
#define VT_S 68
#define PW_S 132
#define X_S  136
#define SM_BYTES (61440 * 2)

// d_ws layout (bytes):
// mask_b bf16 [64][64][c=64] @0           (524288)
// bias_b bf16 [64][4][c=64]  @524288      ( 32768)
// qkvw_b bf16 @557056 (98304); projw_b bf16 @655360 (32768)
#define WS_BIAS_OFF  524288
#define WS_QKVW_OFF  557056
#define WS_PROJW_OFF 655360

__device__ __forceinline__ f32x4 mfmaK32(bf16x8 a, bf16x8 b, f32x4 c) {
  return __builtin_amdgcn_mfma_f32_16x16x32_bf16(a, b, c, 0, 0, 0);
}
__device__ __forceinline__ f32x4 mfmaK16(bf16x4 a, bf16x4 b, f32x4 c) {
#if __has_builtin(__builtin_amdgcn_mfma_f32_16x16x16bf16_1k)
  return __builtin_amdgcn_mfma_f32_16x16x16bf16_1k(*(s16x4*)&a, *(s16x4*)&b, c,
                                                   0, 0, 0);
#else
  f32x4 d;
  asm("v_mfma_f32_16x16x16_bf16 %0, %1, %2, %3"
      : "=v"(d) : "v"(a), "v"(b), "v"(c));
  return d;
#endif
}
__device__ __forceinline__ bf16x8 cvt8p(f32x4 a, f32x4 c) {
  bf16x8 r;
#pragma unroll
  for (int j = 0; j < 4; ++j) { r[j] = (bf16)a[j]; r[4 + j] = (bf16)c[j]; }
  return r;
}
// 16B global read -> two 8B LDS writes (stride-132 rows are 8B-aligned)
__device__ __forceinline__ void stage8(bf16* dst, const bf16* src) {
  bf16x8 v = *(const bf16x8*)src;
  bf16x4 lo, hi;
#pragma unroll
  for (int j = 0; j < 4; ++j) { lo[j] = v[j]; hi[j] = v[4 + j]; }
  *(bf16x4*)dst = lo;
  *(bf16x4*)(dst + 4) = hi;
}

// ---------------- prologue: pack mask, bias, weights into d_ws --------------
// mask_b[win][n][c]: c = quad*16+mt*4+r, m = mt*16+quad*4+r; -30000 at pads.
// bias_b[n][h][c]  : rpb[rel[n][m]][h] — the gather runs 16K times, not 1M.
__global__ __launch_bounds__(256)
void prep(const float* __restrict__ maskg, const float* __restrict__ rpb,
          const int* __restrict__ rel, const float* __restrict__ qkvw,
          const float* __restrict__ projw, bf16* __restrict__ mask_b,
          bf16* __restrict__ bias_b, bf16* __restrict__ qkvw_b,
          bf16* __restrict__ projw_b) {
  int id = blockIdx.x * 256 + threadIdx.x;
  if (id < 262144) {
    int c = id & 63, n = (id >> 6) & 63, win = id >> 12;
    int qd = c >> 4, mt = (c >> 2) & 3, r = c & 3;
    int m = mt * 16 + qd * 4 + r;
    float v = -30000.0f;
    if (n < NTOK && m < NTOK) v = maskg[((size_t)win * NTOK + n) * NTOK + m];
    mask_b[id] = (bf16)v;
  } else if (id < 262144 + 16384) {
    int t = id - 262144;
    int c = t & 63, h = (t >> 6) & 3, n = t >> 8;
    int qd = c >> 4, mt = (c >> 2) & 3, r = c & 3;
    int m = mt * 16 + qd * 4 + r;
    float v = 0.0f;
    if (n < NTOK && m < NTOK) v = rpb[rel[n * NTOK + m] * 4 + h];
    bias_b[t] = (bf16)v;
  } else if (id < 262144 + 16384 + 49152) {
    int t = id - (262144 + 16384);
    qkvw_b[t] = (bf16)qkvw[t];
  } else {
    int t = id - (262144 + 16384 + 49152);
    projw_b[t] = (bf16)projw[t];
  }
}

// ---------------- main kernel: persistent, 1 window/iter, 8 waves ----------
// Phase A: wave w8 owns j-tile w8 of Q,K,V (weights in VGPRs); x frags come
//   from LDS (staged once). Phase B: wave (g=w8&3,hp=w8>>2) does 2 heads of
//   attention for token group g; O^T -> LDS (overlays dead x buffer).
//   Late B: ds_write the prefetched next-window x. Phase C: proj split 8 ways.
// 2 barriers per window; x double-buffered so HBM latency hides under compute.
__global__ __launch_bounds__(512, 2)
void winattn(const float* __restrict__ xg, const float* __restrict__ qkvb,
             const float* __restrict__ projb, const bf16* __restrict__ mask_b,
             const bf16* __restrict__ bias_b, const bf16* __restrict__ qkvw_b,
             const bf16* __restrict__ projw_b, float* __restrict__ out) {
  extern __shared__ bf16 smd[];
  const int tid  = threadIdx.x;
  const int w8   = tid >> 6;
  const int lane = tid & 63;
  const int ln15 = lane & 15;
  const int quad = lane >> 4;
  const int h_kv = w8 >> 1, t_kv = w8 & 1;   // phase A j-tile split
  const int g2   = w8 & 3,  hp   = w8 >> 2;  // phase B/C roles
  const int nq   = g2 * 16 + ln15;

  bf16* __restrict__ pwl = smd + PW_OFF;
  bf16* __restrict__ Kl  = smd + K_OFF;
  bf16* __restrict__ Ql  = smd + Q_OFF;
  bf16* __restrict__ VTl = smd + VT_OFF;

  // ---- one-time: proj weights -> LDS (2048 16B chunks / 512 threads) ----
#pragma unroll
  for (int i = 0; i < 4; ++i) {
    int c = i * 512 + tid;
    int j = c >> 4, kc = (c & 15) * 8;
    stage8(&pwl[j * PW_S + kc], &projw_b[j * DIMC + kc]);
  }

  // ---- one-time: q/k/v weight fragments + biases into registers ----
  bf16x8 wqf[4], wkf[4], wvf[4];
#pragma unroll
  for (int ks = 0; ks < 4; ++ks) {
    wqf[ks] = *(const bf16x8*)&qkvw_b[(size_t)(          w8 * 16 + ln15) * DIMC + ks * 32 + quad * 8];
    wkf[ks] = *(const bf16x8*)&qkvw_b[(size_t)(DIMC    + w8 * 16 + ln15) * DIMC + ks * 32 + quad * 8];
    wvf[ks] = *(const bf16x8*)&qkvw_b[(size_t)(2 * DIMC + w8 * 16 + ln15) * DIMC + ks * 32 + quad * 8];
  }
  f32x4 qb = *(const f32x4*)&qkvb[w8 * 16 + quad * 4];
  f32x4 kb = *(const f32x4*)&qkvb[DIMC + w8 * 16 + quad * 4];
  float vb = qkvb[2 * DIMC + w8 * 16 + ln15];
  f32x4 pb[4];
#pragma unroll
  for (int j = 0; j < 4; ++j)
    pb[j] = *(const f32x4*)&projb[(hp * 4 + j) * 16 + quad * 4];
  bf16x4 bias4[2][4];
#pragma unroll
  for (int hh = 0; hh < 2; ++hh)
#pragma unroll
    for (int mt = 0; mt < 4; ++mt)
      bias4[hh][mt] = *(const bf16x4*)&bias_b[((nq * 4 + hp * 2 + hh) << 6) + quad * 16 + mt * 4];

  // ---- prologue: stage x(window 0) into buffer 0 ----
  {
    const float* x0 = xg + (size_t)(blockIdx.x << 4) * (NTOK * DIMC);
    int r0 = w8 * 8 + quad, r1 = r0 + 4;
    const float* p0 = x0 + (r0 < NTOK ? r0 : NTOK - 1) * DIMC + ln15 * 8;
    const float* p1 = x0 + (r1 < NTOK ? r1 : NTOK - 1) * DIMC + ln15 * 8;
    f32x4 a0 = *(const f32x4*)p0, a1 = *(const f32x4*)(p0 + 4);
    f32x4 a2 = *(const f32x4*)p1, a3 = *(const f32x4*)(p1 + 4);
    *(bf16x8*)&smd[X0_OFF + r0 * X_S + ln15 * 8] = cvt8p(a0, a1);
    *(bf16x8*)&smd[X0_OFF + r1 * X_S + ln15 * 8] = cvt8p(a2, a3);
  }
  __syncthreads();

#pragma unroll 1
  for (int it = 0; it < 16; ++it) {
    const int b = (blockIdx.x << 4) + it;
    bf16* xc = smd + ((it & 1) ? X1_OFF : X0_OFF);
    bf16* xn = smd + ((it & 1) ? X0_OFF : X1_OFF);

    // ---- issue next-window x loads (held in regs until late phase B) ----
    const int nit = it < 15 ? it + 1 : 15;
    const float* xnb = xg + (size_t)((blockIdx.x << 4) + nit) * (NTOK * DIMC);
    const int r0 = w8 * 8 + quad, r1 = r0 + 4;
    const float* np0 = xnb + (r0 < NTOK ? r0 : NTOK - 1) * DIMC + ln15 * 8;
    const float* np1 = xnb + (r1 < NTOK ? r1 : NTOK - 1) * DIMC + ln15 * 8;
    f32x4 nx0 = *(const f32x4*)np0, nx1 = *(const f32x4*)(np0 + 4);
    f32x4 nx2 = *(const f32x4*)np1, nx3 = *(const f32x4*)(np1 + 4);

    // ---- mask prefetch (used in phase B) ----
    const bf16* mb = mask_b + (((size_t)(b & 63) * 64 + nq) << 6) + quad * 16;
    bf16x8 mk0 = *(const bf16x8*)mb;
    bf16x8 mk1 = *(const bf16x8*)(mb + 8);

    // ---- phase A: Q/K/V j-tile w8 for all 4 token groups ----
#pragma unroll
    for (int g = 0; g < 4; ++g) {
      bf16x8 xf[4];
#pragma unroll
      for (int ks = 0; ks < 4; ++ks)
        xf[ks] = *(const bf16x8*)&xc[(g * 16 + ln15) * X_S + ks * 32 + quad * 8];
      f32x4 aq = (f32x4)(0.0f), ak = (f32x4)(0.0f), av = (f32x4)(0.0f);
#pragma unroll
      for (int ks = 0; ks < 4; ++ks) {
        aq = mfmaK32(wqf[ks], xf[ks], aq);   // C[j][tok]
        ak = mfmaK32(wkf[ks], xf[ks], ak);   // C[j][tok]
        av = mfmaK32(xf[ks], wvf[ks], av);   // C[tok][j]
      }
      bf16x4 pq, pk, pv;
#pragma unroll
      for (int r = 0; r < 4; ++r) {
        pq[r] = (bf16)((aq[r] + qb[r]) * SCALE);
        pk[r] = (bf16)(ak[r] + kb[r]);
        pv[r] = (bf16)(av[r] + vb);
      }
      int rowqk = (h_kv * 64 + g * 16 + ln15) * QK_S + t_kv * 16 + quad * 4;
      *(bf16x4*)&Ql[rowqk] = pq;
      *(bf16x4*)&Kl[rowqk] = pk;
      *(bf16x4*)&VTl[(h_kv * 32 + t_kv * 16 + ln15) * VT_S + g * 16 + quad * 4] = pv;
    }
    __syncthreads();   // Q,K,VT ready

    // ---- phase B: 2 heads of attention for token group g2 ----
    bf16* ob = xc;     // O overlay on the (dead) current x buffer
#pragma unroll
    for (int hh = 0; hh < 2; ++hh) {
      const int h = hp * 2 + hh;
      bf16x4 qB0 = *(const bf16x4*)&Ql[(h * 64 + nq) * QK_S + quad * 4];
      bf16x4 qB1 = *(const bf16x4*)&Ql[(h * 64 + nq) * QK_S + 16 + quad * 4];
      f32x4 st[4];
#pragma unroll
      for (int mt = 0; mt < 4; ++mt) {
        const bf16* kr = &Kl[(h * 64 + mt * 16 + ln15) * QK_S + quad * 4];
        st[mt] = mfmaK16(*(const bf16x4*)(kr + 16), qB1,
                 mfmaK16(*(const bf16x4*)kr, qB0, (f32x4)(0.0f)));
      }
      float ssum = 0.0f;
      bf16x4 pw[4];
#pragma unroll
      for (int mt = 0; mt < 4; ++mt)
#pragma unroll
        for (int r = 0; r < 4; ++r) {
          float mv = (mt < 2) ? (float)mk0[mt * 4 + r] : (float)mk1[(mt - 2) * 4 + r];
          float v = fminf(st[mt][r] + mv + (float)bias4[hh][mt][r], 60.0f);
          float p = __expf(v);
          pw[mt][r] = (bf16)p;
          ssum += p;
        }
      ssum += __shfl_xor(ssum, 16);
      ssum += __shfl_xor(ssum, 32);
      f32x4 oa0 = (f32x4)(0.0f), oa1 = (f32x4)(0.0f);
#pragma unroll
      for (int mt = 0; mt < 4; ++mt) {
        oa0 = mfmaK16(*(const bf16x4*)&VTl[(h * 32 + ln15) * VT_S + mt * 16 + quad * 4], pw[mt], oa0);
        oa1 = mfmaK16(*(const bf16x4*)&VTl[(h * 32 + 16 + ln15) * VT_S + mt * 16 + quad * 4], pw[mt], oa1);
      }
      const float inv = 1.0f / ssum;
      bf16x4 o0, o1;
#pragma unroll
      for (int r = 0; r < 4; ++r) {
        o0[r] = (bf16)(oa0[r] * inv);
        o1[r] = (bf16)(oa1[r] * inv);
      }
      *(bf16x4*)&ob[nq * X_S + h * 32 + quad * 4] = o0;
      *(bf16x4*)&ob[nq * X_S + h * 32 + 16 + quad * 4] = o1;
    }

    // ---- late B: commit prefetched x(next) to the other buffer ----
    *(bf16x8*)&xn[r0 * X_S + ln15 * 8] = cvt8p(nx0, nx1);
    *(bf16x8*)&xn[r1 * X_S + ln15 * 8] = cvt8p(nx2, nx3);
    __syncthreads();   // O ready + next-x staged

    // ---- phase C: proj, jt-half hp; flows into next A barrier-free ----
    bf16x4 obf[8];
#pragma unroll
    for (int kt = 0; kt < 8; ++kt)
      obf[kt] = *(const bf16x4*)&ob[nq * X_S + kt * 16 + quad * 4];
    float* og = out + (size_t)b * (NTOK * DIMC) + nq * DIMC;
#pragma unroll
    for (int j = 0; j < 4; ++j) {
      const int jt = hp * 4 + j;
      f32x4 acc = (f32x4)(0.0f);
#pragma unroll
      for (int kt = 0; kt < 8; ++kt)
        acc = mfmaK16(*(const bf16x4*)&pwl[(jt * 16 + ln15) * PW_S + kt * 16 + quad * 4],
                      obf[kt], acc);
      if (nq < NTOK) {
        f32x4 y;
#pragma unroll
        for (int r = 0; r < 4; ++r) y[r] = acc[r] + pb[j][r];
        *(f32x4*)&og[jt * 16 + quad * 4] = y;
      }
    }
  }
}

extern "C" void kernel_launch(void* const* d_in, const int* in_sizes, int n_in,
                              void* d_out, int out_size, void* d_ws, size_t ws_size,
                              hipStream_t stream) {
  const float* x     = (const float*)d_in[0];
  const float* mask  = (const float*)d_in[1];
  const float* qkv_w = (const float*)d_in[2];
  const float* qkv_b = (const float*)d_in[3];
  const float* rpb   = (const float*)d_in[4];
  const float* prj_w = (const float*)d_in[5];
  const float* prj_b = (const float*)d_in[6];
  const int*   rel   = (const int*)d_in[7];
  float* out = (float*)d_out;

  bf16* ws_mask  = (bf16*)d_ws;
  bf16* ws_bias  = (bf16*)((char*)d_ws + WS_BIAS_OFF);
  bf16* ws_qkvw  = (bf16*)((char*)d_ws + WS_QKVW_OFF);
  bf16* ws_projw = (bf16*)((char*)d_ws + WS_PROJW_OFF);

  static int once = []() {
    hipFuncSetAttribute(reinterpret_cast<const void*>(winattn),
                        hipFuncAttributeMaxDynamicSharedMemorySize, SM_BYTES);
    return 0;
  }();
  (void)once;

  prep<<<1344, 256, 0, stream>>>(mask, rpb, rel, qkv_w, prj_w,
                                 ws_mask, ws_bias, ws_qkvw, ws_projw);
  winattn<<<256, 512, SM_BYTES, stream>>>(x, qkv_b, prj_b, ws_mask, ws_bias,
                                          ws_qkvw, ws_projw, out);
}